// Round 6
// baseline (6188.401 us; speedup 1.0000x reference)
//
#include <hip/hip_runtime.h>

typedef unsigned short u16;
typedef unsigned int   u32;

typedef __bf16 bf16x8 __attribute__((ext_vector_type(8)));
typedef float  f32x4  __attribute__((ext_vector_type(4)));

#define NB   64
#define NS   512
#define NE   512
#define NH   1024
#define NK   1536
#define NV   32000

#define WPKF_BYTES  12582912u   // bf16 frags [128 cg][48 kt][2 f][64 lane][8]
#define HFRAG_BYTES 262144u     // bf16 frags 2 par x [4 bg][32 kt][64 lane][8]
#define AEMBF_BYTES 33554432u   // bf16 frags [512 s][4 bg][16 kt][64 lane][8]
#define BSUM_BYTES  16384u      // f32 [4096]
#define BAR_BYTES   32768u      // flags: [2 bgp][128 cg] u32, contiguous

__device__ __forceinline__ u16 f2bf(float f) {
    u32 u = __builtin_bit_cast(u32, f);
    u += 0x7fffu + ((u >> 16) & 1u);       // RNE
    return (u16)(u >> 16);
}
__device__ __forceinline__ bf16x8 pack8(float4 a, float4 b) {
    union { u16 u[8]; bf16x8 v; } o;
    o.u[0]=f2bf(a.x); o.u[1]=f2bf(a.y); o.u[2]=f2bf(a.z); o.u[3]=f2bf(a.w);
    o.u[4]=f2bf(b.x); o.u[5]=f2bf(b.y); o.u[6]=f2bf(b.z); o.u[7]=f2bf(b.w);
    return o.v;
}
__device__ __forceinline__ float sigf(float x) {
    return __frcp_rn(1.0f + __expf(-x));
}
__device__ __forceinline__ float tanhf_fast(float x) {
    return 1.0f - 2.0f * __frcp_rn(__expf(2.0f * x) + 1.0f);
}
__device__ __forceinline__ int clamptok(int t) {
    return t < 0 ? 0 : (t >= NV ? NV - 1 : t);
}

// ---------------------------------------------------------------------------
// Prep kernels
// ---------------------------------------------------------------------------
__global__ void init_state(const float* __restrict__ h0,
                           const float* __restrict__ c0,
                           float* __restrict__ out) {
    int i = blockIdx.x * 256 + threadIdx.x;
    float* out_h = out + 64;
    float* out_c = out + 64 + NB * NH;
    ((float4*)out_h)[i] = ((const float4*)h0)[i];
    ((float4*)out_c)[i] = ((const float4*)c0)[i];
}

__global__ void init_hfrag(const float* __restrict__ h0,
                           u16* __restrict__ hfrag0) {
    int blk = blockIdx.x, lane = threadIdx.x;
    int bg = blk >> 5, kt = blk & 31;
    int n16 = lane & 15, quad = lane >> 4;
    int b = bg * 16 + n16;
    int k = kt * 32 + quad * 8;
    const float* src = h0 + (size_t)b * NH + k;
    union { bf16x8 v; uint4 q; } o;
    o.v = pack8(*(const float4*)src, *(const float4*)(src + 4));
    *(uint4*)(hfrag0 + ((size_t)blk * 64 + lane) * 8) = o.q;
}

__global__ void prep_wfrag(const float* __restrict__ Wih,
                           const float* __restrict__ Whh,
                           u16* __restrict__ wpkf) {
    int blk = blockIdx.x, t = threadIdx.x;
    int cg = blk / 48, kt = blk % 48;
    int f = t >> 6, lane = t & 63;
    int n16 = lane & 15, quad = lane >> 4;
    int nl = f * 16 + n16;
    int j = (nl >> 3) * NH + cg * 8 + (nl & 7);
    int k = kt * 32 + quad * 8;
    const float* src = (k < NH) ? (Whh + (size_t)j * NH + k)
                                : (Wih + (size_t)j * NE + (k - NH));
    union { bf16x8 v; uint4 q; } o;
    o.v = pack8(*(const float4*)src, *(const float4*)(src + 4));
    *(uint4*)(wpkf + (((size_t)blk * 2 + f) * 64 + lane) * 8) = o.q;
}

__global__ void prep_aembf(const int* __restrict__ x,
                           const float* __restrict__ emb,
                           u16* __restrict__ aembf) {
    int blk = blockIdx.x, t = threadIdx.x;
    int s = blk >> 2, bg = blk & 3;
#pragma unroll
    for (int i = 0; i < 4; ++i) {
        int u = t + i * 256;
        int kt16 = u >> 6, lane = u & 63;
        int n16 = lane & 15, quad = lane >> 4;
        int b = bg * 16 + n16;
        int tok = clamptok(x[b * NS + s]);
        const float* ep = emb + (size_t)tok * NE + kt16 * 32 + quad * 8;
        union { bf16x8 v; uint4 q; } o;
        o.v = pack8(*(const float4*)ep, *(const float4*)(ep + 4));
        *(uint4*)(aembf + (((size_t)blk * 16 + kt16) * 64 + lane) * 8) = o.q;
    }
}

__global__ void prep_bsum(const float* __restrict__ bih,
                          const float* __restrict__ bhh,
                          float* __restrict__ bsum,
                          unsigned* __restrict__ bar) {
    int i = blockIdx.x * 256 + threadIdx.x;   // grid 16x256 -> [0,4096)
    bsum[i] = bih[i] + bhh[i];
    bar[i] = 0u;                               // zero all flag words
    bar[i + 4096] = 0u;
}

// ---------------------------------------------------------------------------
// Persistent cooperative kernel. 256 blocks x 256 thr (4 waves, 1 block/CU).
// XCD-aligned swizzle: bgp = (blk&7)>>2 so each XCD hosts one bgp only.
// Weights: 96KB cg-slice staged to LDS once; per-step ds_read_b128.
// h exchange: producers publish via agent-scope (through-to-IF) stores;
// consumers use PLAIN L2-cached loads after a per-wave acquire(agent) fence
// (buffer_inv). First toucher per XCD pulls IF->L2 once; 32 blocks share ->
// IF h-read traffic drops ~16x vs sc0/sc1-direct reads.
// Barrier: contiguous flag array per bgp (128 x u32). Publish drain ->
// tid0 stores own flag -> ALL waves poll all 128 flags with ONE coalesced
// dwordx2/lane sc0/sc1 load -> no post-poll sync (waves decouple).
// ---------------------------------------------------------------------------
template<bool EMBF>
__device__ __forceinline__ void persist_body(
    const int* __restrict__ x, const float* __restrict__ emb,
    const u16* __restrict__ wpkf, const u16* __restrict__ aembf,
    u16* __restrict__ hf0, u16* __restrict__ hf1,
    const float* __restrict__ bsum, const float* __restrict__ c0,
    float* __restrict__ cstate, float* __restrict__ out_h,
    unsigned* __restrict__ bar)
{
    const int tid  = threadIdx.x;
    const int lane = tid & 63;
    const int w    = tid >> 6;             // 0..3
    const int blk  = blockIdx.x;
    // XCD-aligned decomposition: XCD = blk&7 (round-robin dispatch);
    // XCDs 0-3 -> bgp 0, XCDs 4-7 -> bgp 1.
    const int c7   = blk & 7;
    const int bgp  = c7 >> 2;
    const int cg   = (blk >> 3) * 4 + (c7 & 3);
    const int quad = lane >> 4;
    const int n16  = lane & 15;

    __shared__ u16   lw[48 * 2 * 64 * 8];  // 96KB weight slice
    __shared__ float part[4][32][36];      // 18KB K-partials (pad 36: 2-way free)

    // ---- stage weight slice into LDS once ----
    {
        const uint4* src = (const uint4*)(wpkf + (size_t)cg * (48 * 2 * 64 * 8));
        uint4* dst = (uint4*)lw;
#pragma unroll
        for (int i = 0; i < 24; ++i)
            dst[i * 256 + tid] = src[i * 256 + tid];
    }

    // ---- epilogue constants: bias + c pinned in registers ----
    const int mloc = tid >> 3;             // 0..31
    const int uu   = tid & 7;
    const int be   = bgp * 32 + mloc;
    const int je   = cg * 8 + uu;
    const float bp0 = bsum[0 * NH + je];
    const float bp1 = bsum[1 * NH + je];
    const float bp2 = bsum[2 * NH + je];
    const float bp3 = bsum[3 * NH + je];
    float c_reg = c0[(size_t)be * NH + je];

    // h publish address pieces (dword-packed pair stores)
    const int kth   = cg >> 2;
    const int lane2 = (cg & 3) * 16 + (mloc & 15);
    const int bgW   = bgp * 2 + (mloc >> 4);
    const size_t hwo_base = ((size_t)(bgW * 32 + kth) * 64 + lane2) * 8;

    const int bg0 = bgp * 2, bg1 = bg0 + 1;

    // ---- flags: contiguous u32 per bgp; own word + coalesced poll span ----
    unsigned* my_flag = bar + bgp * 128 + cg;
    const unsigned* pf = bar + bgp * 128 + lane * 2;   // 2 flags per lane

    // ---- emb A-frag prefetch (h-independent, hidden under the barrier) ----
    bf16x8 ea0[4], ea1[4];
    auto loadE = [&](int s) {
        if (EMBF) {
            const u16* e0 = aembf + ((size_t)(s * 4 + bg0) * 16) * (64 * 8);
            const u16* e1 = aembf + ((size_t)(s * 4 + bg1) * 16) * (64 * 8);
#pragma unroll
            for (int i = 0; i < 4; ++i) {
                int ke = w * 4 + i;
                ea0[i] = *(const bf16x8*)(e0 + ((size_t)ke * 64 + lane) * 8);
                ea1[i] = *(const bf16x8*)(e1 + ((size_t)ke * 64 + lane) * 8);
            }
        } else {
            int t0 = clamptok(x[(bg0 * 16 + n16) * NS + s]);
            int t1 = clamptok(x[(bg1 * 16 + n16) * NS + s]);
            const float* p0 = emb + (size_t)t0 * NE + quad * 8;
            const float* p1 = emb + (size_t)t1 * NE + quad * 8;
#pragma unroll
            for (int i = 0; i < 4; ++i) {
                int ko = (w * 4 + i) * 32;
                ea0[i] = pack8(*(const float4*)(p0 + ko), *(const float4*)(p0 + ko + 4));
                ea1[i] = pack8(*(const float4*)(p1 + ko), *(const float4*)(p1 + ko + 4));
            }
        }
    };
    loadE(0);
    __syncthreads();                       // LDS weight staging complete

#pragma unroll 1
    for (int s = 0; s < NS; ++s) {
        const u16* hb = (s & 1) ? hf1 : hf0;
        u16*       ho = (s & 1) ? hf0 : hf1;
        const u16* hb0 = hb + (size_t)(bg0 * 32) * (64 * 8);
        const u16* hb1 = hb + (size_t)(bg1 * 32) * (64 * 8);

        // ---- plain L2-cached h loads (fence at end of prev iter) ----
        uint4 hv0[8], hv1[8];
#pragma unroll
        for (int i = 0; i < 8; ++i) {
            hv0[i] = *(const uint4*)(hb0 + ((size_t)((w * 8 + i) * 64 + lane)) * 8);
            hv1[i] = *(const uint4*)(hb1 + ((size_t)((w * 8 + i) * 64 + lane)) * 8);
        }

        f32x4 acc00 = {0.f,0.f,0.f,0.f}, acc01 = {0.f,0.f,0.f,0.f};
        f32x4 acc10 = {0.f,0.f,0.f,0.f}, acc11 = {0.f,0.f,0.f,0.f};

        // ---- emb MFMAs while h loads are in flight ----
#pragma unroll
        for (int i = 0; i < 4; ++i) {
            int kt = 32 + w * 4 + i;
            bf16x8 w0 = *(const bf16x8*)(lw + ((size_t)(kt * 2 + 0) * 64 + lane) * 8);
            bf16x8 w1 = *(const bf16x8*)(lw + ((size_t)(kt * 2 + 1) * 64 + lane) * 8);
            acc00 = __builtin_amdgcn_mfma_f32_16x16x32_bf16(ea0[i], w0, acc00, 0, 0, 0);
            acc01 = __builtin_amdgcn_mfma_f32_16x16x32_bf16(ea0[i], w1, acc01, 0, 0, 0);
            acc10 = __builtin_amdgcn_mfma_f32_16x16x32_bf16(ea1[i], w0, acc10, 0, 0, 0);
            acc11 = __builtin_amdgcn_mfma_f32_16x16x32_bf16(ea1[i], w1, acc11, 0, 0, 0);
        }

        // ---- h MFMAs (compiler inserts waitcnt for hv deps) ----
#pragma unroll
        for (int i = 0; i < 8; ++i) {
            int kt = w * 8 + i;
            bf16x8 a0 = __builtin_bit_cast(bf16x8, hv0[i]);
            bf16x8 a1 = __builtin_bit_cast(bf16x8, hv1[i]);
            bf16x8 w0 = *(const bf16x8*)(lw + ((size_t)(kt * 2 + 0) * 64 + lane) * 8);
            bf16x8 w1 = *(const bf16x8*)(lw + ((size_t)(kt * 2 + 1) * 64 + lane) * 8);
            acc00 = __builtin_amdgcn_mfma_f32_16x16x32_bf16(a0, w0, acc00, 0, 0, 0);
            acc01 = __builtin_amdgcn_mfma_f32_16x16x32_bf16(a0, w1, acc01, 0, 0, 0);
            acc10 = __builtin_amdgcn_mfma_f32_16x16x32_bf16(a1, w0, acc10, 0, 0, 0);
            acc11 = __builtin_amdgcn_mfma_f32_16x16x32_bf16(a1, w1, acc11, 0, 0, 0);
        }

        {   // D layout: row=(lane>>4)*4+r (batch), col=lane&15
            int mrow = quad * 4;
#pragma unroll
            for (int r = 0; r < 4; ++r) {
                part[w][mrow + r][n16]           = acc00[r];
                part[w][mrow + r][16 + n16]      = acc01[r];
                part[w][16 + mrow + r][n16]      = acc10[r];
                part[w][16 + mrow + r][16 + n16] = acc11[r];
            }
        }
        __syncthreads();                   // sync#1: part[] ready

        // ---- reduce + gates + state update (all 256 threads) ----
        float hN;
        {
            float gv0 = bp0, gv1 = bp1, gv2 = bp2, gv3 = bp3;
#pragma unroll
            for (int ww = 0; ww < 4; ++ww) {
                gv0 += part[ww][mloc][ 0 + uu];
                gv1 += part[ww][mloc][ 8 + uu];
                gv2 += part[ww][mloc][16 + uu];
                gv3 += part[ww][mloc][24 + uu];
            }
            float iS = sigf(gv0);
            float fS = sigf(gv1);
            float gT = tanhf_fast(gv2);
            float oS = sigf(gv3);
            float c_new = fS * c_reg + iS * gT;
            c_new = fminf(20.0f, fmaxf(-20.0f, c_new));
            c_reg = c_new;
            hN = oS * tanhf_fast(c_new);
        }

        if (s == NS - 1) {
            out_h[(size_t)be * NH + je]  = hN;
            cstate[(size_t)be * NH + je] = c_reg;
        } else {
            const unsigned need = (unsigned)(s + 1);
            // ---- publish h: pack (uu, uu+1) via shfl, one dword store ----
            u32 hbf = f2bf(hN);
            u32 hup = (u32)__shfl_down((int)hbf, 1);
            if ((uu & 1) == 0) {
                u32 val = hbf | (hup << 16);
                u32* dst = (u32*)(ho + hwo_base + uu);
                __hip_atomic_store(dst, val, __ATOMIC_RELAXED,
                                   __HIP_MEMORY_SCOPE_AGENT);
            }
            asm volatile("s_waitcnt vmcnt(0)" ::: "memory");
            __syncthreads();               // sync#2: all waves drained (+part consumed)
            if (tid == 0)
                __hip_atomic_store(my_flag, need, __ATOMIC_RELAXED,
                                   __HIP_MEMORY_SCOPE_AGENT);
            loadE(s + 1);                  // emb prefetch rides the poll window
            // ---- coalesced all-flag poll: dwordx2/lane covers 128 flags ----
            {
                uint2 v;
                while (true) {
                    asm volatile("global_load_dwordx2 %0, %1, off sc0 sc1\n\t"
                                 "s_waitcnt vmcnt(0)"
                                 : "=v"(v) : "v"(pf) : "memory");
                    if (__all(v.x >= need && v.y >= need)) break;
                    __builtin_amdgcn_s_sleep(1);
                }
            }
            // acquire: invalidate stale L1/L2 lines before next h reads
            __builtin_amdgcn_fence(__ATOMIC_ACQUIRE, "agent");
            // no post-poll block barrier: waves decouple until sync#1
        }
    }
}

__global__ void __launch_bounds__(256, 1)
lstm_persist_a(const int* __restrict__ x, const float* __restrict__ emb,
               const u16* __restrict__ wpkf, const u16* __restrict__ aembf,
               u16* __restrict__ hf0, u16* __restrict__ hf1,
               const float* __restrict__ bsum, const float* __restrict__ c0,
               float* __restrict__ cstate, float* __restrict__ out_h,
               unsigned* __restrict__ bar) {
    persist_body<true>(x, emb, wpkf, aembf, hf0, hf1, bsum, c0, cstate, out_h, bar);
}

__global__ void __launch_bounds__(256, 1)
lstm_persist_b(const int* __restrict__ x, const float* __restrict__ emb,
               const u16* __restrict__ wpkf, const u16* __restrict__ aembf,
               u16* __restrict__ hf0, u16* __restrict__ hf1,
               const float* __restrict__ bsum, const float* __restrict__ c0,
               float* __restrict__ cstate, float* __restrict__ out_h,
               unsigned* __restrict__ bar) {
    persist_body<false>(x, emb, wpkf, aembf, hf0, hf1, bsum, c0, cstate, out_h, bar);
}

// ---------------------------------------------------------------------------
// Raw fallback (tiny ws): f32 weights + in-flight pack, f32 h ping.
// ---------------------------------------------------------------------------
__global__ void __launch_bounds__(256)
lstm_step_raw(const int* __restrict__ x, const float* __restrict__ emb,
              const float* __restrict__ Wih, const float* __restrict__ Whh,
              const float* __restrict__ bih, const float* __restrict__ bhh,
              const float* __restrict__ hA, float* __restrict__ hB,
              float* __restrict__ cbuf, int s) {
    const int tid  = threadIdx.x;
    const int lane = tid & 63;
    const int w    = tid >> 6;
    const int blk  = blockIdx.x;
    const int cg   = blk & 127;
    const int bg   = blk >> 7;
    const int u0   = cg * 8;
    const int b0   = bg * 16;

    __shared__ float part[4][16][36];
    const int n16 = lane & 15;
    const int kq  = (lane >> 4) * 8;
    const int tok = clamptok(x[(b0 + n16) * NS + s]);

    const int nl0 = n16, nl1 = 16 + n16;
    const int r0 = (nl0 >> 3) * NH + u0 + (nl0 & 7);
    const int r1 = (nl1 >> 3) * NH + u0 + (nl1 & 7);

    f32x4 acc0 = {0.f,0.f,0.f,0.f};
    f32x4 acc1 = {0.f,0.f,0.f,0.f};

#pragma unroll
    for (int tkt = 0; tkt < 12; ++tkt) {
        int kt = w * 12 + tkt;
        int ko = kt * 32 + kq;
        const float *s0, *s1;
        if (kt < 32) { s0 = Whh + (size_t)r0 * NH + ko; s1 = Whh + (size_t)r1 * NH + ko; }
        else         { s0 = Wih + (size_t)r0 * NE + (ko - NH); s1 = Wih + (size_t)r1 * NE + (ko - NH); }
        bf16x8 wf0 = pack8(*(const float4*)s0, *(const float4*)(s0 + 4));
        bf16x8 wf1 = pack8(*(const float4*)s1, *(const float4*)(s1 + 4));
        bf16x8 a0;
        if (kt < 32) {
            const float* hp = hA + (size_t)(b0 + n16) * NH + ko;
            a0 = pack8(*(const float4*)hp, *(const float4*)(hp + 4));
        } else {
            const float* ep = emb + (size_t)tok * NE + (ko - NH);
            a0 = pack8(*(const float4*)ep, *(const float4*)(ep + 4));
        }
        acc0 = __builtin_amdgcn_mfma_f32_16x16x32_bf16(a0, wf0, acc0, 0, 0, 0);
        acc1 = __builtin_amdgcn_mfma_f32_16x16x32_bf16(a0, wf1, acc1, 0, 0, 0);
    }

    {
        int mrow = (lane >> 4) * 4;
#pragma unroll
        for (int r = 0; r < 4; ++r) {
            part[w][mrow + r][n16]      = acc0[r];
            part[w][mrow + r][16 + n16] = acc1[r];
        }
    }
    __syncthreads();

    if (tid < 128) {
        const int mloc = tid >> 3, uu = tid & 7;
        const int be = b0 + mloc, je = u0 + uu;
        float gv[4];
#pragma unroll
        for (int g = 0; g < 4; ++g) {
            int n = g * 8 + uu;
            gv[g] = part[0][mloc][n] + part[1][mloc][n]
                  + part[2][mloc][n] + part[3][mloc][n]
                  + bih[g * NH + je] + bhh[g * NH + je];
        }
        float iS = sigf(gv[0]);
        float fS = sigf(gv[1]);
        float gT = tanhf_fast(gv[2]);
        float oS = sigf(gv[3]);
        float c_new = fS * cbuf[be * NH + je] + iS * gT;
        c_new = fminf(20.0f, fmaxf(-20.0f, c_new));
        float hN = oS * tanhf_fast(c_new);
        cbuf[be * NH + je] = c_new;
        hB[be * NH + je]   = hN;
    }
}

__global__ void final_fc_simple(const float* __restrict__ fc_w,
                                const float* __restrict__ fc_b,
                                float* __restrict__ out) {
    __shared__ float red[64][5];
    const float* out_h = out + 64;
    int t = threadIdx.x;
    int b = t >> 2, q = t & 3;
    const float* hp = out_h + b * NH + q * 256;
    const float* wp = fc_w + q * 256;
    float sacc = 0.f;
#pragma unroll 4
    for (int i = 0; i < 64; ++i) {
        float4 hv = ((const float4*)hp)[i];
        float4 wv = ((const float4*)wp)[i];
        sacc += hv.x * wv.x + hv.y * wv.y + hv.z * wv.z + hv.w * wv.w;
    }
    red[b][q] = sacc;
    __syncthreads();
    if (q == 0) {
        float tot = red[b][0] + red[b][1] + red[b][2] + red[b][3] + fc_b[0];
        out[b] = 1.0f / (1.0f + expf(-tot));
    }
}

extern "C" void kernel_launch(void* const* d_in, const int* in_sizes, int n_in,
                              void* d_out, int out_size, void* d_ws, size_t ws_size,
                              hipStream_t stream) {
    // order: x, h0, c0, emb, W_ih, W_hh, b_ih, b_hh, fc_w, fc_b
    const int*   x   = (const int*)d_in[0];
    const float* h0  = (const float*)d_in[1];
    const float* c0  = (const float*)d_in[2];
    const float* emb = (const float*)d_in[3];
    const float* Wih = (const float*)d_in[4];
    const float* Whh = (const float*)d_in[5];
    const float* bih = (const float*)d_in[6];
    const float* bhh = (const float*)d_in[7];
    const float* fcw = (const float*)d_in[8];
    const float* fcb = (const float*)d_in[9];

    float* out   = (float*)d_out;
    float* out_h = out + 64;
    float* out_c = out + 64 + NB * NH;       // c state in-place

    const size_t needA = (size_t)WPKF_BYTES + HFRAG_BYTES + AEMBF_BYTES + BSUM_BYTES + BAR_BYTES;
    const size_t needB = (size_t)WPKF_BYTES + HFRAG_BYTES + BSUM_BYTES + BAR_BYTES;
    const bool tierA = ws_size >= needA;
    const bool tierB = !tierA && ws_size >= needB;

    if (tierA || tierB) {
        // out_h/out_c fully overwritten at s=NS-1 by the persistent kernel.
        u16* wpkf  = (u16*)d_ws;
        u16* hfrag = (u16*)((char*)d_ws + WPKF_BYTES);
        u16* hf0 = hfrag;
        u16* hf1 = hfrag + HFRAG_BYTES / 4;  // u16 elems per parity
        char* after = (char*)d_ws + WPKF_BYTES + HFRAG_BYTES;
        u16*   aembf = tierA ? (u16*)after : nullptr;
        float* bsum  = (float*)(after + (tierA ? AEMBF_BYTES : 0));
        unsigned* bar = (unsigned*)((char*)bsum + BSUM_BYTES);

        hipLaunchKernelGGL(init_hfrag, dim3(128), dim3(64), 0, stream, h0, hf0);
        hipLaunchKernelGGL(prep_wfrag, dim3(6144), dim3(128), 0, stream,
                           Wih, Whh, wpkf);
        hipLaunchKernelGGL(prep_bsum, dim3(16), dim3(256), 0, stream,
                           bih, bhh, bsum, bar);
        if (tierA)
            hipLaunchKernelGGL(prep_aembf, dim3(2048), dim3(256), 0, stream,
                               x, emb, aembf);

        void* kargs[11] = { &x, &emb, &wpkf, &aembf, &hf0, &hf1,
                            &bsum, &c0, &out_c, &out_h, &bar };
        (void)hipLaunchCooperativeKernel(
            tierA ? reinterpret_cast<const void*>(&lstm_persist_a)
                  : reinterpret_cast<const void*>(&lstm_persist_b),
            dim3(256), dim3(256), kargs, 0u, stream);
    } else {
        hipLaunchKernelGGL(init_state, dim3(64), dim3(256), 0, stream, h0, c0, out);
        float* wsH = (float*)d_ws;
        for (int s = 0; s < NS; ++s) {
            const float* hA = (s & 1) ? wsH : out_h;
            float*       hB = (s & 1) ? out_h : wsH;   // s=511 odd -> out_h
            hipLaunchKernelGGL(lstm_step_raw, dim3(512), dim3(256), 0, stream,
                               x, emb, Wih, Whh, bih, bhh, hA, hB, out_c, s);
        }
    }

    hipLaunchKernelGGL(final_fc_simple, dim3(1), dim3(256), 0, stream,
                       fcw, fcb, out);
}

// Round 7
// 1745.071 us; speedup vs baseline: 3.5462x; 3.5462x over previous
//
#include <hip/hip_runtime.h>

typedef unsigned short u16;
typedef unsigned int   u32;

typedef __bf16 bf16x8 __attribute__((ext_vector_type(8)));
typedef float  f32x4  __attribute__((ext_vector_type(4)));

#define NB   64
#define NS   512
#define NE   512
#define NH   1024
#define NK   1536
#define NV   32000

#define WPKF_BYTES  12582912u   // bf16 frags [128 cg][48 kt][2 f][64 lane][8]
#define HFRAG_BYTES 262144u     // bf16 frags 2 par x [4 bg][32 kt][64 lane][8]
#define AEMBF_BYTES 33554432u   // bf16 frags [512 s][4 bg][16 kt][64 lane][8]
#define BSUM_BYTES  16384u      // f32 [4096]
#define BAR_BYTES   32768u      // flags: [2 bgp][128 cg] at 128B spacing

__device__ __forceinline__ u16 f2bf(float f) {
    u32 u = __builtin_bit_cast(u32, f);
    u += 0x7fffu + ((u >> 16) & 1u);       // RNE
    return (u16)(u >> 16);
}
__device__ __forceinline__ bf16x8 pack8(float4 a, float4 b) {
    union { u16 u[8]; bf16x8 v; } o;
    o.u[0]=f2bf(a.x); o.u[1]=f2bf(a.y); o.u[2]=f2bf(a.z); o.u[3]=f2bf(a.w);
    o.u[4]=f2bf(b.x); o.u[5]=f2bf(b.y); o.u[6]=f2bf(b.z); o.u[7]=f2bf(b.w);
    return o.v;
}
__device__ __forceinline__ float sigf(float x) {
    return __frcp_rn(1.0f + __expf(-x));
}
__device__ __forceinline__ float tanhf_fast(float x) {
    return 1.0f - 2.0f * __frcp_rn(__expf(2.0f * x) + 1.0f);
}
__device__ __forceinline__ int clamptok(int t) {
    return t < 0 ? 0 : (t >= NV ? NV - 1 : t);
}

// ---------------------------------------------------------------------------
// Prep kernels
// ---------------------------------------------------------------------------
__global__ void init_state(const float* __restrict__ h0,
                           const float* __restrict__ c0,
                           float* __restrict__ out) {
    int i = blockIdx.x * 256 + threadIdx.x;
    float* out_h = out + 64;
    float* out_c = out + 64 + NB * NH;
    ((float4*)out_h)[i] = ((const float4*)h0)[i];
    ((float4*)out_c)[i] = ((const float4*)c0)[i];
}

__global__ void init_hfrag(const float* __restrict__ h0,
                           u16* __restrict__ hfrag0) {
    int blk = blockIdx.x, lane = threadIdx.x;
    int bg = blk >> 5, kt = blk & 31;
    int n16 = lane & 15, quad = lane >> 4;
    int b = bg * 16 + n16;
    int k = kt * 32 + quad * 8;
    const float* src = h0 + (size_t)b * NH + k;
    union { bf16x8 v; uint4 q; } o;
    o.v = pack8(*(const float4*)src, *(const float4*)(src + 4));
    *(uint4*)(hfrag0 + ((size_t)blk * 64 + lane) * 8) = o.q;
}

__global__ void prep_wfrag(const float* __restrict__ Wih,
                           const float* __restrict__ Whh,
                           u16* __restrict__ wpkf) {
    int blk = blockIdx.x, t = threadIdx.x;
    int cg = blk / 48, kt = blk % 48;
    int f = t >> 6, lane = t & 63;
    int n16 = lane & 15, quad = lane >> 4;
    int nl = f * 16 + n16;
    int j = (nl >> 3) * NH + cg * 8 + (nl & 7);
    int k = kt * 32 + quad * 8;
    const float* src = (k < NH) ? (Whh + (size_t)j * NH + k)
                                : (Wih + (size_t)j * NE + (k - NH));
    union { bf16x8 v; uint4 q; } o;
    o.v = pack8(*(const float4*)src, *(const float4*)(src + 4));
    *(uint4*)(wpkf + (((size_t)blk * 2 + f) * 64 + lane) * 8) = o.q;
}

__global__ void prep_aembf(const int* __restrict__ x,
                           const float* __restrict__ emb,
                           u16* __restrict__ aembf) {
    int blk = blockIdx.x, t = threadIdx.x;
    int s = blk >> 2, bg = blk & 3;
#pragma unroll
    for (int i = 0; i < 4; ++i) {
        int u = t + i * 256;
        int kt16 = u >> 6, lane = u & 63;
        int n16 = lane & 15, quad = lane >> 4;
        int b = bg * 16 + n16;
        int tok = clamptok(x[b * NS + s]);
        const float* ep = emb + (size_t)tok * NE + kt16 * 32 + quad * 8;
        union { bf16x8 v; uint4 q; } o;
        o.v = pack8(*(const float4*)ep, *(const float4*)(ep + 4));
        *(uint4*)(aembf + (((size_t)blk * 16 + kt16) * 64 + lane) * 8) = o.q;
    }
}

__global__ void prep_bsum(const float* __restrict__ bih,
                          const float* __restrict__ bhh,
                          float* __restrict__ bsum,
                          unsigned* __restrict__ bar) {
    int i = blockIdx.x * 256 + threadIdx.x;   // grid 16x256 -> [0,4096)
    bsum[i] = bih[i] + bhh[i];
    bar[i] = 0u;                               // zero all flag lines (32KB)
    bar[i + 4096] = 0u;
}

// ---------------------------------------------------------------------------
// Persistent cooperative kernel. 256 blocks x 256 thr (4 waves, 1 block/CU).
// blk = cg(128) x bgp(2); the two bgp halves are fully independent.
// Weights: 96KB cg-slice staged to LDS once; per-step ds_read_b128.
// h exchange: device-coherent sc0/sc1 accesses straight to IF (R4-proven:
// no fences anywhere -> L2-resident weights/emb are never invalidated).
// Barrier: DEPENDENCY-EXACT per-wave flags. Consumer wave w needs only
// h frags kt in [8w,8w+8), produced exactly by blocks cg in [32w,32w+32).
// So wave w polls just those 32 flags (2 lanes/line) and proceeds
// immediately -- no block-wide poll, no post-poll sync. part[] reuse is
// guarded by sync#2 (all part reads precede publish in program order).
// ---------------------------------------------------------------------------
template<bool EMBF>
__device__ __forceinline__ void persist_body(
    const int* __restrict__ x, const float* __restrict__ emb,
    const u16* __restrict__ wpkf, const u16* __restrict__ aembf,
    u16* __restrict__ hf0, u16* __restrict__ hf1,
    const float* __restrict__ bsum, const float* __restrict__ c0,
    float* __restrict__ cstate, float* __restrict__ out_h,
    unsigned* __restrict__ bar)
{
    const int tid  = threadIdx.x;
    const int lane = tid & 63;
    const int w    = tid >> 6;             // 0..3
    const int blk  = blockIdx.x;
    const int cg   = blk & 127;
    const int bgp  = blk >> 7;
    const int quad = lane >> 4;
    const int n16  = lane & 15;

    __shared__ u16   lw[48 * 2 * 64 * 8];  // 96KB weight slice
    __shared__ float part[4][32][36];      // 18KB K-partials (pad 36: 2-way free)

    // ---- stage weight slice into LDS once ----
    {
        const uint4* src = (const uint4*)(wpkf + (size_t)cg * (48 * 2 * 64 * 8));
        uint4* dst = (uint4*)lw;
#pragma unroll
        for (int i = 0; i < 24; ++i)
            dst[i * 256 + tid] = src[i * 256 + tid];
    }

    // ---- epilogue constants: bias + c pinned in registers ----
    const int mloc = tid >> 3;             // 0..31
    const int uu   = tid & 7;
    const int be   = bgp * 32 + mloc;
    const int je   = cg * 8 + uu;
    const float bp0 = bsum[0 * NH + je];
    const float bp1 = bsum[1 * NH + je];
    const float bp2 = bsum[2 * NH + je];
    const float bp3 = bsum[3 * NH + je];
    float c_reg = c0[(size_t)be * NH + je];

    // h publish address pieces (dword-packed pair stores)
    const int kth   = cg >> 2;
    const int lane2 = (cg & 3) * 16 + (mloc & 15);
    const int bgW   = bgp * 2 + (mloc >> 4);
    const size_t hwo_base = ((size_t)(bgW * 32 + kth) * 64 + lane2) * 8;

    const int bg0 = bgp * 2, bg1 = bg0 + 1;

    // ---- barrier flags: own line + this wave's 32 producer lines ----
    unsigned* my_flag = bar + ((size_t)(bgp * 128 + cg) * 32);
    const unsigned* pw_flag =
        bar + ((size_t)(bgp * 128 + w * 32 + (lane & 31)) * 32);

    // ---- emb A-frag prefetch (h-independent, hidden under the barrier) ----
    bf16x8 ea0[4], ea1[4];
    auto loadE = [&](int s) {
        if (EMBF) {
            const u16* e0 = aembf + ((size_t)(s * 4 + bg0) * 16) * (64 * 8);
            const u16* e1 = aembf + ((size_t)(s * 4 + bg1) * 16) * (64 * 8);
#pragma unroll
            for (int i = 0; i < 4; ++i) {
                int ke = w * 4 + i;
                ea0[i] = *(const bf16x8*)(e0 + ((size_t)ke * 64 + lane) * 8);
                ea1[i] = *(const bf16x8*)(e1 + ((size_t)ke * 64 + lane) * 8);
            }
        } else {
            int t0 = clamptok(x[(bg0 * 16 + n16) * NS + s]);
            int t1 = clamptok(x[(bg1 * 16 + n16) * NS + s]);
            const float* p0 = emb + (size_t)t0 * NE + quad * 8;
            const float* p1 = emb + (size_t)t1 * NE + quad * 8;
#pragma unroll
            for (int i = 0; i < 4; ++i) {
                int ko = (w * 4 + i) * 32;
                ea0[i] = pack8(*(const float4*)(p0 + ko), *(const float4*)(p0 + ko + 4));
                ea1[i] = pack8(*(const float4*)(p1 + ko), *(const float4*)(p1 + ko + 4));
            }
        }
    };
    loadE(0);
    __syncthreads();                       // LDS weight staging complete

#pragma unroll 1
    for (int s = 0; s < NS; ++s) {
        const u16* hb = (s & 1) ? hf1 : hf0;
        u16*       ho = (s & 1) ? hf0 : hf1;
        const u16* hb0 = hb + (size_t)(bg0 * 32) * (64 * 8);
        const u16* hb1 = hb + (size_t)(bg1 * 32) * (64 * 8);

        f32x4 acc00 = {0.f,0.f,0.f,0.f}, acc01 = {0.f,0.f,0.f,0.f};
        f32x4 acc10 = {0.f,0.f,0.f,0.f}, acc11 = {0.f,0.f,0.f,0.f};

        // ---- issue device-coherent h loads (16 in flight) ----
        uint4 hv0[8], hv1[8];
#pragma unroll
        for (int i = 0; i < 8; ++i) {
            const u16* a0p = hb0 + ((size_t)((w * 8 + i) * 64 + lane)) * 8;
            const u16* a1p = hb1 + ((size_t)((w * 8 + i) * 64 + lane)) * 8;
            asm volatile("global_load_dwordx4 %0, %1, off sc0 sc1"
                         : "=v"(hv0[i]) : "v"(a0p) : "memory");
            asm volatile("global_load_dwordx4 %0, %1, off sc0 sc1"
                         : "=v"(hv1[i]) : "v"(a1p) : "memory");
        }

        // ---- emb MFMAs while h loads are in flight ----
#pragma unroll
        for (int i = 0; i < 4; ++i) {
            int kt = 32 + w * 4 + i;
            bf16x8 w0 = *(const bf16x8*)(lw + ((size_t)(kt * 2 + 0) * 64 + lane) * 8);
            bf16x8 w1 = *(const bf16x8*)(lw + ((size_t)(kt * 2 + 1) * 64 + lane) * 8);
            acc00 = __builtin_amdgcn_mfma_f32_16x16x32_bf16(ea0[i], w0, acc00, 0, 0, 0);
            acc01 = __builtin_amdgcn_mfma_f32_16x16x32_bf16(ea0[i], w1, acc01, 0, 0, 0);
            acc10 = __builtin_amdgcn_mfma_f32_16x16x32_bf16(ea1[i], w0, acc10, 0, 0, 0);
            acc11 = __builtin_amdgcn_mfma_f32_16x16x32_bf16(ea1[i], w1, acc11, 0, 0, 0);
        }

        asm volatile("s_waitcnt vmcnt(0)" ::: "memory");
        __builtin_amdgcn_sched_barrier(0);

        // ---- h MFMAs ----
#pragma unroll
        for (int i = 0; i < 8; ++i) {
            int kt = w * 8 + i;
            bf16x8 a0 = __builtin_bit_cast(bf16x8, hv0[i]);
            bf16x8 a1 = __builtin_bit_cast(bf16x8, hv1[i]);
            bf16x8 w0 = *(const bf16x8*)(lw + ((size_t)(kt * 2 + 0) * 64 + lane) * 8);
            bf16x8 w1 = *(const bf16x8*)(lw + ((size_t)(kt * 2 + 1) * 64 + lane) * 8);
            acc00 = __builtin_amdgcn_mfma_f32_16x16x32_bf16(a0, w0, acc00, 0, 0, 0);
            acc01 = __builtin_amdgcn_mfma_f32_16x16x32_bf16(a0, w1, acc01, 0, 0, 0);
            acc10 = __builtin_amdgcn_mfma_f32_16x16x32_bf16(a1, w0, acc10, 0, 0, 0);
            acc11 = __builtin_amdgcn_mfma_f32_16x16x32_bf16(a1, w1, acc11, 0, 0, 0);
        }

        {   // D layout: row=(lane>>4)*4+r (batch), col=lane&15
            int mrow = quad * 4;
#pragma unroll
            for (int r = 0; r < 4; ++r) {
                part[w][mrow + r][n16]           = acc00[r];
                part[w][mrow + r][16 + n16]      = acc01[r];
                part[w][16 + mrow + r][n16]      = acc10[r];
                part[w][16 + mrow + r][16 + n16] = acc11[r];
            }
        }
        __syncthreads();                   // sync#1: part[] ready

        // ---- reduce + gates + state update (all 256 threads) ----
        float hN;
        {
            float gv0 = bp0, gv1 = bp1, gv2 = bp2, gv3 = bp3;
#pragma unroll
            for (int ww = 0; ww < 4; ++ww) {
                gv0 += part[ww][mloc][ 0 + uu];
                gv1 += part[ww][mloc][ 8 + uu];
                gv2 += part[ww][mloc][16 + uu];
                gv3 += part[ww][mloc][24 + uu];
            }
            float iS = sigf(gv0);
            float fS = sigf(gv1);
            float gT = tanhf_fast(gv2);
            float oS = sigf(gv3);
            float c_new = fS * c_reg + iS * gT;
            c_new = fminf(20.0f, fmaxf(-20.0f, c_new));
            c_reg = c_new;
            hN = oS * tanhf_fast(c_new);
        }

        if (s == NS - 1) {
            out_h[(size_t)be * NH + je]  = hN;
            cstate[(size_t)be * NH + je] = c_reg;
        } else {
            const unsigned need = (unsigned)(s + 1);
            // ---- publish h: pack (uu, uu+1) via shfl, one dword store ----
            u32 hbf = f2bf(hN);
            u32 hup = (u32)__shfl_down((int)hbf, 1);
            if ((uu & 1) == 0) {
                u32 val = hbf | (hup << 16);
                u32* dst = (u32*)(ho + hwo_base + uu);
                __hip_atomic_store(dst, val, __ATOMIC_RELAXED,
                                   __HIP_MEMORY_SCOPE_AGENT);
            }
            asm volatile("s_waitcnt vmcnt(0)" ::: "memory");
            __syncthreads();               // sync#2: publishes drained + part consumed
            if (tid == 0)
                __hip_atomic_store(my_flag, need, __ATOMIC_RELAXED,
                                   __HIP_MEMORY_SCOPE_AGENT);
            loadE(s + 1);                  // emb prefetch rides the poll window
            // ---- dependency-exact poll: this wave's 32 producers only ----
            {
                unsigned v;
                while (true) {
                    asm volatile("global_load_dword %0, %1, off sc0 sc1\n\t"
                                 "s_waitcnt vmcnt(0)"
                                 : "=v"(v) : "v"(pw_flag) : "memory");
                    if (__all(v >= need)) break;
                    __builtin_amdgcn_s_sleep(1);
                }
            }
            // no post-poll barrier: wave proceeds straight to its h loads
        }
    }
}

__global__ void __launch_bounds__(256, 1)
lstm_persist_a(const int* __restrict__ x, const float* __restrict__ emb,
               const u16* __restrict__ wpkf, const u16* __restrict__ aembf,
               u16* __restrict__ hf0, u16* __restrict__ hf1,
               const float* __restrict__ bsum, const float* __restrict__ c0,
               float* __restrict__ cstate, float* __restrict__ out_h,
               unsigned* __restrict__ bar) {
    persist_body<true>(x, emb, wpkf, aembf, hf0, hf1, bsum, c0, cstate, out_h, bar);
}

__global__ void __launch_bounds__(256, 1)
lstm_persist_b(const int* __restrict__ x, const float* __restrict__ emb,
               const u16* __restrict__ wpkf, const u16* __restrict__ aembf,
               u16* __restrict__ hf0, u16* __restrict__ hf1,
               const float* __restrict__ bsum, const float* __restrict__ c0,
               float* __restrict__ cstate, float* __restrict__ out_h,
               unsigned* __restrict__ bar) {
    persist_body<false>(x, emb, wpkf, aembf, hf0, hf1, bsum, c0, cstate, out_h, bar);
}

// ---------------------------------------------------------------------------
// Raw fallback (tiny ws): f32 weights + in-flight pack, f32 h ping.
// ---------------------------------------------------------------------------
__global__ void __launch_bounds__(256)
lstm_step_raw(const int* __restrict__ x, const float* __restrict__ emb,
              const float* __restrict__ Wih, const float* __restrict__ Whh,
              const float* __restrict__ bih, const float* __restrict__ bhh,
              const float* __restrict__ hA, float* __restrict__ hB,
              float* __restrict__ cbuf, int s) {
    const int tid  = threadIdx.x;
    const int lane = tid & 63;
    const int w    = tid >> 6;
    const int blk  = blockIdx.x;
    const int cg   = blk & 127;
    const int bg   = blk >> 7;
    const int u0   = cg * 8;
    const int b0   = bg * 16;

    __shared__ float part[4][16][36];
    const int n16 = lane & 15;
    const int kq  = (lane >> 4) * 8;
    const int tok = clamptok(x[(b0 + n16) * NS + s]);

    const int nl0 = n16, nl1 = 16 + n16;
    const int r0 = (nl0 >> 3) * NH + u0 + (nl0 & 7);
    const int r1 = (nl1 >> 3) * NH + u0 + (nl1 & 7);

    f32x4 acc0 = {0.f,0.f,0.f,0.f};
    f32x4 acc1 = {0.f,0.f,0.f,0.f};

#pragma unroll
    for (int tkt = 0; tkt < 12; ++tkt) {
        int kt = w * 12 + tkt;
        int ko = kt * 32 + kq;
        const float *s0, *s1;
        if (kt < 32) { s0 = Whh + (size_t)r0 * NH + ko; s1 = Whh + (size_t)r1 * NH + ko; }
        else         { s0 = Wih + (size_t)r0 * NE + (ko - NH); s1 = Wih + (size_t)r1 * NE + (ko - NH); }
        bf16x8 wf0 = pack8(*(const float4*)s0, *(const float4*)(s0 + 4));
        bf16x8 wf1 = pack8(*(const float4*)s1, *(const float4*)(s1 + 4));
        bf16x8 a0;
        if (kt < 32) {
            const float* hp = hA + (size_t)(b0 + n16) * NH + ko;
            a0 = pack8(*(const float4*)hp, *(const float4*)(hp + 4));
        } else {
            const float* ep = emb + (size_t)tok * NE + (ko - NH);
            a0 = pack8(*(const float4*)ep, *(const float4*)(ep + 4));
        }
        acc0 = __builtin_amdgcn_mfma_f32_16x16x32_bf16(a0, wf0, acc0, 0, 0, 0);
        acc1 = __builtin_amdgcn_mfma_f32_16x16x32_bf16(a0, wf1, acc1, 0, 0, 0);
    }

    {
        int mrow = (lane >> 4) * 4;
#pragma unroll
        for (int r = 0; r < 4; ++r) {
            part[w][mrow + r][n16]      = acc0[r];
            part[w][mrow + r][16 + n16] = acc1[r];
        }
    }
    __syncthreads();

    if (tid < 128) {
        const int mloc = tid >> 3, uu = tid & 7;
        const int be = b0 + mloc, je = u0 + uu;
        float gv[4];
#pragma unroll
        for (int g = 0; g < 4; ++g) {
            int n = g * 8 + uu;
            gv[g] = part[0][mloc][n] + part[1][mloc][n]
                  + part[2][mloc][n] + part[3][mloc][n]
                  + bih[g * NH + je] + bhh[g * NH + je];
        }
        float iS = sigf(gv[0]);
        float fS = sigf(gv[1]);
        float gT = tanhf_fast(gv[2]);
        float oS = sigf(gv[3]);
        float c_new = fS * cbuf[be * NH + je] + iS * gT;
        c_new = fminf(20.0f, fmaxf(-20.0f, c_new));
        float hN = oS * tanhf_fast(c_new);
        cbuf[be * NH + je] = c_new;
        hB[be * NH + je]   = hN;
    }
}

__global__ void final_fc_simple(const float* __restrict__ fc_w,
                                const float* __restrict__ fc_b,
                                float* __restrict__ out) {
    __shared__ float red[64][5];
    const float* out_h = out + 64;
    int t = threadIdx.x;
    int b = t >> 2, q = t & 3;
    const float* hp = out_h + b * NH + q * 256;
    const float* wp = fc_w + q * 256;
    float sacc = 0.f;
#pragma unroll 4
    for (int i = 0; i < 64; ++i) {
        float4 hv = ((const float4*)hp)[i];
        float4 wv = ((const float4*)wp)[i];
        sacc += hv.x * wv.x + hv.y * wv.y + hv.z * wv.z + hv.w * wv.w;
    }
    red[b][q] = sacc;
    __syncthreads();
    if (q == 0) {
        float tot = red[b][0] + red[b][1] + red[b][2] + red[b][3] + fc_b[0];
        out[b] = 1.0f / (1.0f + expf(-tot));
    }
}

extern "C" void kernel_launch(void* const* d_in, const int* in_sizes, int n_in,
                              void* d_out, int out_size, void* d_ws, size_t ws_size,
                              hipStream_t stream) {
    // order: x, h0, c0, emb, W_ih, W_hh, b_ih, b_hh, fc_w, fc_b
    const int*   x   = (const int*)d_in[0];
    const float* h0  = (const float*)d_in[1];
    const float* c0  = (const float*)d_in[2];
    const float* emb = (const float*)d_in[3];
    const float* Wih = (const float*)d_in[4];
    const float* Whh = (const float*)d_in[5];
    const float* bih = (const float*)d_in[6];
    const float* bhh = (const float*)d_in[7];
    const float* fcw = (const float*)d_in[8];
    const float* fcb = (const float*)d_in[9];

    float* out   = (float*)d_out;
    float* out_h = out + 64;
    float* out_c = out + 64 + NB * NH;       // c state in-place

    const size_t needA = (size_t)WPKF_BYTES + HFRAG_BYTES + AEMBF_BYTES + BSUM_BYTES + BAR_BYTES;
    const size_t needB = (size_t)WPKF_BYTES + HFRAG_BYTES + BSUM_BYTES + BAR_BYTES;
    const bool tierA = ws_size >= needA;
    const bool tierB = !tierA && ws_size >= needB;

    if (tierA || tierB) {
        // out_h/out_c fully overwritten at s=NS-1 by the persistent kernel.
        u16* wpkf  = (u16*)d_ws;
        u16* hfrag = (u16*)((char*)d_ws + WPKF_BYTES);
        u16* hf0 = hfrag;
        u16* hf1 = hfrag + HFRAG_BYTES / 4;  // u16 elems per parity
        char* after = (char*)d_ws + WPKF_BYTES + HFRAG_BYTES;
        u16*   aembf = tierA ? (u16*)after : nullptr;
        float* bsum  = (float*)(after + (tierA ? AEMBF_BYTES : 0));
        unsigned* bar = (unsigned*)((char*)bsum + BSUM_BYTES);

        hipLaunchKernelGGL(init_hfrag, dim3(128), dim3(64), 0, stream, h0, hf0);
        hipLaunchKernelGGL(prep_wfrag, dim3(6144), dim3(128), 0, stream,
                           Wih, Whh, wpkf);
        hipLaunchKernelGGL(prep_bsum, dim3(16), dim3(256), 0, stream,
                           bih, bhh, bsum, bar);
        if (tierA)
            hipLaunchKernelGGL(prep_aembf, dim3(2048), dim3(256), 0, stream,
                               x, emb, aembf);

        void* kargs[11] = { &x, &emb, &wpkf, &aembf, &hf0, &hf1,
                            &bsum, &c0, &out_c, &out_h, &bar };
        (void)hipLaunchCooperativeKernel(
            tierA ? reinterpret_cast<const void*>(&lstm_persist_a)
                  : reinterpret_cast<const void*>(&lstm_persist_b),
            dim3(256), dim3(256), kargs, 0u, stream);
    } else {
        hipLaunchKernelGGL(init_state, dim3(64), dim3(256), 0, stream, h0, c0, out);
        float* wsH = (float*)d_ws;
        for (int s = 0; s < NS; ++s) {
            const float* hA = (s & 1) ? wsH : out_h;
            float*       hB = (s & 1) ? out_h : wsH;   // s=511 odd -> out_h
            hipLaunchKernelGGL(lstm_step_raw, dim3(512), dim3(256), 0, stream,
                               x, emb, Wih, Whh, bih, bhh, hA, hB, out_c, s);
        }
    }

    hipLaunchKernelGGL(final_fc_simple, dim3(1), dim3(256), 0, stream,
                       fcw, fcb, out);
}